// Round 4
// baseline (1124.510 us; speedup 1.0000x reference)
//
#include <hip/hip_runtime.h>

// SSIM, single fused wave-autonomous streaming kernel.
// x,y: [16,3,512,512] f32; window: [3,1,11,11] f32 (separable Gaussian).
// Output: scalar mean SSIM (f32).
//
// Each 64-thread block (one wave) owns a 64-col x 32-row output strip and
// streams 43 input rows top-to-bottom:
//   - one 74-wide x/y row staged in DOUBLE-BUFFERED wave-private LDS; exactly
//     one __syncthreads() per row between store and cross-lane read (the R3
//     version had no barrier -> compiler hoisted reads across the write: race)
//   - horizontal 11-tap conv of {x, y, x^2, y^2, x*y} per lane (22 LDS reads,
//     stride-1, conflict-free)
//   - vertical 11-tap conv via a 5x11 REGISTER ring (static indices by
//     unroll-by-11), zero LDS traffic
//   - global loads prefetched one row ahead
// Final mean via last-block reduction (agent-scope atomics), one dispatch.

#define IMG_H 512
#define IMG_W 512
#define NC    48                   // 16 batches * 3 channels

constexpr int STRIP = 32;                    // output rows per wave
constexpr int NSX = IMG_W / 64;              // 8 column tiles
constexpr int NSY = IMG_H / STRIP;           // 16 row strips
constexpr int NWAVES = NSX * NSY * NC;       // 6144 blocks (1 wave each)

__global__ __launch_bounds__(64, 4)
void ssim_stream(const float* __restrict__ x, const float* __restrict__ y,
                 const float* __restrict__ w, double* __restrict__ part,
                 int* __restrict__ counter, float* __restrict__ out)
{
    __shared__ float sb[2][2][80];           // [buf][x|y][staged col]

    const int lane = threadIdx.x;            // block == one wave
    const int x0 = blockIdx.x * 64;
    const int r0 = blockIdx.y * STRIP;
    const float* __restrict__ xp = x + (size_t)blockIdx.z * (IMG_H * IMG_W);
    const float* __restrict__ yp = y + (size_t)blockIdx.z * (IMG_H * IMG_W);

    // 1D gaussian from window row 5: w2d[5][k] = g5*g[k], g5 = sqrt(w[60]).
    float g[11];
    {
        const float gi = 1.0f / sqrtf(w[60]);
        #pragma unroll
        for (int k = 0; k < 11; ++k) g[k] = w[55 + k] * gi;
    }

    // Staged cols x0-5 .. x0+68 (74). Lane l -> col x0-5+l; lanes 0..9 also
    // cover col x0+59+l. OOB cols clamped then zeroed.
    const int  c0   = x0 - 5 + lane;
    const int  c0c  = min(max(c0, 0), IMG_W - 1);
    const bool c0ok = (c0 >= 0) & (c0 < IMG_W);
    const int  c1   = c0 + 64;
    const int  c1c  = min(c1, IMG_W - 1);
    const bool c1ok = (c1 < IMG_W);

    struct Row { float a0, a1, b0, b1; };

    auto load_row = [&](int t) -> Row {
        Row r;
        const int  tc  = min(max(t, 0), IMG_H - 1);
        const bool tok = (t >= 0) & (t < IMG_H);
        const float* __restrict__ xr = xp + (size_t)tc * IMG_W;
        const float* __restrict__ yr = yp + (size_t)tc * IMG_W;
        const float va = xr[c0c];
        const float vb = yr[c0c];
        r.a0 = (tok & c0ok) ? va : 0.0f;
        r.b0 = (tok & c0ok) ? vb : 0.0f;
        r.a1 = 0.0f; r.b1 = 0.0f;
        if (lane < 10) {
            const float wa = xr[c1c];
            const float wb = yr[c1c];
            r.a1 = (tok & c1ok) ? wa : 0.0f;
            r.b1 = (tok & c1ok) ? wb : 0.0f;
        }
        return r;
    };

    auto store_row = [&](int pb, const Row& r) {
        sb[pb][0][lane] = r.a0;
        sb[pb][1][lane] = r.b0;
        if (lane < 10) { sb[pb][0][lane + 64] = r.a1; sb[pb][1][lane + 64] = r.b1; }
    };

    // horizontal 11-tap conv of {x,y,xx,yy,xy} for this lane's column
    auto compute_h = [&](int pb, float& h0, float& h1, float& h2, float& h3,
                         float& h4) {
        h0 = h1 = h2 = h3 = h4 = 0.0f;
        #pragma unroll
        for (int k = 0; k < 11; ++k) {
            const float a = sb[pb][0][lane + k];
            const float b = sb[pb][1][lane + k];
            const float gk = g[k];
            h0 = fmaf(gk, a,     h0);
            h1 = fmaf(gk, b,     h1);
            h2 = fmaf(gk, a * a, h2);
            h3 = fmaf(gk, b * b, h3);
            h4 = fmaf(gk, a * b, h4);
        }
    };

    float ring[5][11];
    int pb = 0;

    // ---- prologue: rows r0-5 .. r0+4 into ring slots 0..9
    Row pf = load_row(r0 - 5);
    #pragma unroll
    for (int i = 0; i < 10; ++i) {
        store_row(pb, pf);
        pf = load_row(r0 - 4 + i);
        __syncthreads();   // RAW: cross-lane reads below see this row's stores
        compute_h(pb, ring[0][i], ring[1][i], ring[2][i], ring[3][i], ring[4][i]);
        pb ^= 1;
    }

    // ---- main loop: 33 iterations (32 outputs + 1 spare for unroll-11 tiling)
    const float C1 = 1e-4f;   // 0.01^2
    const float C2 = 9e-4f;   // 0.03^2
    float lsum = 0.0f;

    for (int a = 0; a < 3; ++a) {
        #pragma unroll
        for (int u = 0; u < 11; ++u) {
            const int j = a * 11 + u;       // output row index in strip
            store_row(pb, pf);
            pf = load_row(r0 + 6 + j);      // prefetch next (OOB -> 0)
            __syncthreads();
            // row r0+5+j -> slot (10+j)%11 == (10+u)%11 (static after unroll)
            const int sl = (10 + u) % 11;
            compute_h(pb, ring[0][sl], ring[1][sl], ring[2][sl], ring[3][sl],
                      ring[4][sl]);
            pb ^= 1;

            if (j < STRIP) {
                float m1 = 0.f, m2 = 0.f, sxx = 0.f, syy = 0.f, sxy = 0.f;
                #pragma unroll
                for (int k = 0; k < 11; ++k) {
                    const int s = (u + k) % 11;   // (j+k)%11, static after unroll
                    const float gk = g[k];
                    m1  = fmaf(gk, ring[0][s], m1);
                    m2  = fmaf(gk, ring[1][s], m2);
                    sxx = fmaf(gk, ring[2][s], sxx);
                    syy = fmaf(gk, ring[3][s], syy);
                    sxy = fmaf(gk, ring[4][s], sxy);
                }
                const float m1s = m1 * m1, m2s = m2 * m2, m12 = m1 * m2;
                const float v1  = sxx - m1s;
                const float v2  = syy - m2s;
                const float v12 = sxy - m12;
                const float num = (2.0f * m12 + C1) * (2.0f * v12 + C2);
                const float den = (m1s + m2s + C1) * (v1 + v2 + C2);
                lsum += num / den;
            }
        }
    }

    // ---- wave reduction
    #pragma unroll
    for (int off = 32; off > 0; off >>= 1)
        lsum += __shfl_down(lsum, off, 64);

    const int wid = blockIdx.x + NSX * (blockIdx.y + NSY * blockIdx.z);
    int old = 0;
    if (lane == 0) {
        __hip_atomic_store(&part[wid], (double)lsum,
                           __ATOMIC_RELEASE, __HIP_MEMORY_SCOPE_AGENT);
        old = __hip_atomic_fetch_add(counter, 1,
                                     __ATOMIC_ACQ_REL, __HIP_MEMORY_SCOPE_AGENT);
    }
    old = __shfl(old, 0, 64);

    // ---- last block reduces all partials (acquire loads: pair with releases)
    if (old == NWAVES - 1) {
        double s = 0.0;
        for (int i = lane; i < NWAVES; i += 64)
            s += __hip_atomic_load(&part[i], __ATOMIC_ACQUIRE,
                                   __HIP_MEMORY_SCOPE_AGENT);
        #pragma unroll
        for (int off = 32; off > 0; off >>= 1)
            s += __shfl_down(s, off, 64);
        if (lane == 0)
            out[0] = (float)(s / (double)((size_t)NC * IMG_H * IMG_W));
    }
}

extern "C" void kernel_launch(void* const* d_in, const int* in_sizes, int n_in,
                              void* d_out, int out_size, void* d_ws, size_t ws_size,
                              hipStream_t stream)
{
    const float* x = (const float*)d_in[0];
    const float* y = (const float*)d_in[1];
    const float* w = (const float*)d_in[2];

    int*    counter = (int*)d_ws;                          // 4 B
    double* part    = (double*)((char*)d_ws + 16);         // 6144 doubles

    hipMemsetAsync(counter, 0, sizeof(int), stream);

    dim3 grid(NSX, NSY, NC);     // (8, 16, 48) = 6144 single-wave blocks
    ssim_stream<<<grid, 64, 0, stream>>>(x, y, w, part, counter, (float*)d_out);
}

// Round 5
// 691.106 us; speedup vs baseline: 1.6271x; 1.6271x over previous
//
#include <hip/hip_runtime.h>
#include <utility>

// SSIM, single fused wave-autonomous streaming kernel.
// x,y: [16,3,512,512] f32; window: [3,1,11,11] f32 (separable Gaussian).
// Output: scalar mean SSIM (f32).
//
// Each 64-thread block (one wave) owns a 64-col x 32-row output strip and
// streams 43 input rows top-to-bottom:
//   - one 74-wide x/y row staged in DOUBLE-BUFFERED wave-private LDS; one
//     __syncthreads() per row between store and cross-lane read
//   - horizontal 11-tap conv of {x, y, x^2, y^2, x*y} per lane (22 LDS reads,
//     stride-1, conflict-free)
//   - vertical 11-tap conv via a 5x11 REGISTER ring
//   - R4 lesson: #pragma unroll loops with barriers did NOT unroll -> ring
//     indices dynamic -> ring demoted to scratch (1.2 GB spill traffic).
//     All ring-touching / barrier-containing loops are now integer_sequence
//     folds (sfor<N>) -- straight-line code, indices constexpr by construction.
// Final mean via last-block reduction (agent-scope atomics), one dispatch.

#define IMG_H 512
#define IMG_W 512
#define NC    48                   // 16 batches * 3 channels

constexpr int STRIP = 32;                    // output rows per wave
constexpr int NSX = IMG_W / 64;              // 8 column tiles
constexpr int NSY = IMG_H / STRIP;           // 16 row strips
constexpr int NWAVES = NSX * NSY * NC;       // 6144 blocks (1 wave each)

template <typename F, int... Is>
__device__ __forceinline__ void sfor_impl(F&& f, std::integer_sequence<int, Is...>) {
    (f(std::integral_constant<int, Is>{}), ...);
}
template <int N, typename F>
__device__ __forceinline__ void sfor(F&& f) {
    sfor_impl((F&&)f, std::make_integer_sequence<int, N>{});
}

__global__ __launch_bounds__(64, 2)
void ssim_stream(const float* __restrict__ x, const float* __restrict__ y,
                 const float* __restrict__ w, double* __restrict__ part,
                 int* __restrict__ counter, float* __restrict__ out)
{
    __shared__ float sb[2][2][80];           // [buf][x|y][staged col]

    const int lane = threadIdx.x;            // block == one wave
    const int x0 = blockIdx.x * 64;
    const int r0 = blockIdx.y * STRIP;
    const float* __restrict__ xp = x + (size_t)blockIdx.z * (IMG_H * IMG_W);
    const float* __restrict__ yp = y + (size_t)blockIdx.z * (IMG_H * IMG_W);

    // 1D gaussian from window row 5: w2d[5][k] = g5*g[k], g5 = sqrt(w[60]).
    float g[11];
    {
        const float gi = 1.0f / sqrtf(w[60]);
        sfor<11>([&](auto K) { constexpr int k = K.value; g[k] = w[55 + k] * gi; });
    }

    // Staged cols x0-5 .. x0+68 (74). Lane l -> col x0-5+l; lanes 0..9 also
    // cover col x0+59+l. OOB cols clamped then zeroed.
    const int  c0   = x0 - 5 + lane;
    const int  c0c  = min(max(c0, 0), IMG_W - 1);
    const bool c0ok = (c0 >= 0) & (c0 < IMG_W);
    const int  c1   = c0 + 64;
    const int  c1c  = min(c1, IMG_W - 1);
    const bool c1ok = (c1 < IMG_W);

    struct Row { float a0, a1, b0, b1; };

    auto load_row = [&](int t) -> Row {
        Row r;
        const int  tc  = min(max(t, 0), IMG_H - 1);
        const bool tok = (t >= 0) & (t < IMG_H);
        const float* __restrict__ xr = xp + (size_t)tc * IMG_W;
        const float* __restrict__ yr = yp + (size_t)tc * IMG_W;
        const float va = xr[c0c];
        const float vb = yr[c0c];
        r.a0 = (tok & c0ok) ? va : 0.0f;
        r.b0 = (tok & c0ok) ? vb : 0.0f;
        r.a1 = 0.0f; r.b1 = 0.0f;
        if (lane < 10) {
            const float wa = xr[c1c];
            const float wb = yr[c1c];
            r.a1 = (tok & c1ok) ? wa : 0.0f;
            r.b1 = (tok & c1ok) ? wb : 0.0f;
        }
        return r;
    };

    auto store_row = [&](int pb, const Row& r) {
        sb[pb][0][lane] = r.a0;
        sb[pb][1][lane] = r.b0;
        if (lane < 10) { sb[pb][0][lane + 64] = r.a1; sb[pb][1][lane + 64] = r.b1; }
    };

    // horizontal 11-tap conv of {x,y,xx,yy,xy} for this lane's column
    auto compute_h = [&](int pb, float& h0, float& h1, float& h2, float& h3,
                         float& h4) {
        h0 = h1 = h2 = h3 = h4 = 0.0f;
        sfor<11>([&](auto K) {
            constexpr int k = K.value;
            const float a = sb[pb][0][lane + k];
            const float b = sb[pb][1][lane + k];
            const float gk = g[k];
            h0 = fmaf(gk, a,     h0);
            h1 = fmaf(gk, b,     h1);
            h2 = fmaf(gk, a * a, h2);
            h3 = fmaf(gk, b * b, h3);
            h4 = fmaf(gk, a * b, h4);
        });
    };

    float r0g[11], r1g[11], r2g[11], r3g[11], r4g[11];   // the register ring

    // ---- prologue: rows r0-5 .. r0+4 into ring slots 0..9
    Row pf = load_row(r0 - 5);
    sfor<10>([&](auto I) {
        constexpr int i = I.value;
        store_row(i & 1, pf);
        pf = load_row(r0 - 4 + i);
        __syncthreads();   // RAW: cross-lane reads below see this row's stores
        compute_h(i & 1, r0g[i], r1g[i], r2g[i], r3g[i], r4g[i]);
    });

    // ---- main loop: 33 stages (32 outputs + 1 spare for the mod-11 tiling)
    const float C1 = 1e-4f;   // 0.01^2
    const float C2 = 9e-4f;   // 0.03^2
    float lsum = 0.0f;
    int pb = 0;               // 10 prologue toggles -> back to buffer 0

    for (int a = 0; a < 3; ++a) {
        sfor<11>([&](auto U) {
            constexpr int u = U.value;
            const int j = a * 11 + u;       // output row index in strip
            store_row(pb, pf);
            pf = load_row(r0 + 6 + j);      // prefetch next (OOB -> 0)
            __syncthreads();
            constexpr int sl = (10 + u) % 11;   // slot of row r0+5+j
            compute_h(pb, r0g[sl], r1g[sl], r2g[sl], r3g[sl], r4g[sl]);
            pb ^= 1;

            if (j < STRIP) {
                float m1 = 0.f, m2 = 0.f, sxx = 0.f, syy = 0.f, sxy = 0.f;
                sfor<11>([&](auto K) {
                    constexpr int k = K.value;
                    constexpr int s = (u + k) % 11;   // (j+k)%11
                    const float gk = g[k];
                    m1  = fmaf(gk, r0g[s], m1);
                    m2  = fmaf(gk, r1g[s], m2);
                    sxx = fmaf(gk, r2g[s], sxx);
                    syy = fmaf(gk, r3g[s], syy);
                    sxy = fmaf(gk, r4g[s], sxy);
                });
                const float m1s = m1 * m1, m2s = m2 * m2, m12 = m1 * m2;
                const float v1  = sxx - m1s;
                const float v2  = syy - m2s;
                const float v12 = sxy - m12;
                const float num = (2.0f * m12 + C1) * (2.0f * v12 + C2);
                const float den = (m1s + m2s + C1) * (v1 + v2 + C2);
                lsum += num / den;
            }
        });
    }

    // ---- wave reduction
    #pragma unroll
    for (int off = 32; off > 0; off >>= 1)
        lsum += __shfl_down(lsum, off, 64);

    const int wid = blockIdx.x + NSX * (blockIdx.y + NSY * blockIdx.z);
    int old = 0;
    if (lane == 0) {
        __hip_atomic_store(&part[wid], (double)lsum,
                           __ATOMIC_RELEASE, __HIP_MEMORY_SCOPE_AGENT);
        old = __hip_atomic_fetch_add(counter, 1,
                                     __ATOMIC_ACQ_REL, __HIP_MEMORY_SCOPE_AGENT);
    }
    old = __shfl(old, 0, 64);

    // ---- last block reduces all partials (acquire loads pair with releases)
    if (old == NWAVES - 1) {
        double s = 0.0;
        for (int i = lane; i < NWAVES; i += 64)
            s += __hip_atomic_load(&part[i], __ATOMIC_ACQUIRE,
                                   __HIP_MEMORY_SCOPE_AGENT);
        #pragma unroll
        for (int off = 32; off > 0; off >>= 1)
            s += __shfl_down(s, off, 64);
        if (lane == 0)
            out[0] = (float)(s / (double)((size_t)NC * IMG_H * IMG_W));
    }
}

extern "C" void kernel_launch(void* const* d_in, const int* in_sizes, int n_in,
                              void* d_out, int out_size, void* d_ws, size_t ws_size,
                              hipStream_t stream)
{
    const float* x = (const float*)d_in[0];
    const float* y = (const float*)d_in[1];
    const float* w = (const float*)d_in[2];

    int*    counter = (int*)d_ws;                          // 4 B
    double* part    = (double*)((char*)d_ws + 16);         // 6144 doubles

    hipMemsetAsync(counter, 0, sizeof(int), stream);

    dim3 grid(NSX, NSY, NC);     // (8, 16, 48) = 6144 single-wave blocks
    ssim_stream<<<grid, 64, 0, stream>>>(x, y, w, part, counter, (float*)d_out);
}